// Round 9
// baseline (99.644 us; speedup 1.0000x reference)
//
#include <hip/hip_runtime.h>
#include <hip/hip_bf16.h>
#include <stdint.h>

#define BATCH 8
#define SEQN  4096
#define DIM   128
#define NT    32              // 32-kv tiles per quarter (1024 kv)

typedef __attribute__((ext_vector_type(16))) float f32x16;
typedef __bf16 bf16x8 __attribute__((ext_vector_type(8)));

#define GAS __attribute__((address_space(1)))
#define LAS __attribute__((address_space(3)))

__device__ __forceinline__ ushort f2b(float x) {
  union { float f; uint32_t u; } a; a.f = x;
  uint32_t r = a.u + 0x7fffu + ((a.u >> 16) & 1u);   // RNE
  return (ushort)(r >> 16);
}
__device__ __forceinline__ uint32_t pkbf(float a, float b) {
  union { __bf16 h[2]; uint32_t u; } x;
  x.h[0] = (__bf16)a; x.h[1] = (__bf16)b;
  return x.u;
}

// Fragment-major layouts, per 32-row chunk g (global row/32), 4096 elems/chunk:
//   Q/K: slot = (kc*2+hi)*32 + ql holds  X[g*32+ql][16*kc+8*hi + 0..7]
//   V^T: slot = (db*4+ks*2+hi)*32 + ql holds V[g*32 + 16*ks+8*hi + 0..7][32*db+ql]

__global__ __launch_bounds__(256) void prep_fused(
    const float* __restrict__ qk, const float* __restrict__ v,
    ushort* __restrict__ qfb, ushort* __restrict__ kfb, ushort* __restrict__ vfb) {
  __shared__ ushort qt_l[32 * 136];
  __shared__ ushort kt_l[32 * 136];
  __shared__ ushort vt_l[32 * 136];
  const int g = blockIdx.x;
  const int t = threadIdx.x;
  const int r = t >> 3, s = t & 7;
  {
    const float* src = qk + (size_t)g * 4096 + r * 128 + s * 16;
    float x[16];
    #pragma unroll
    for (int i = 0; i < 4; ++i) {
      float4 f = ((const float4*)src)[i];
      x[4*i] = f.x; x[4*i+1] = f.y; x[4*i+2] = f.z; x[4*i+3] = f.w;
    }
    float ss = 0.f;
    #pragma unroll
    for (int i = 0; i < 16; ++i) ss += x[i] * x[i];
    ss += __shfl_xor(ss, 1, 64);
    ss += __shfl_xor(ss, 2, 64);
    ss += __shfl_xor(ss, 4, 64);
    float rn = 1.0f / fmaxf(sqrtf(ss), 1e-12f);
    const float SC = 1.44269504088896340736f / 11.313708498984761f; // log2e/sqrt(128)
    float rs = rn * SC;
    #pragma unroll
    for (int j = 0; j < 16; ++j) {
      qt_l[r * 136 + s * 16 + j] = f2b(x[j]);
      kt_l[r * 136 + s * 16 + j] = f2b(x[j] * rs);
    }
  }
  {
    const float* src = v + (size_t)g * 4096 + r * 128 + s * 16;
    #pragma unroll
    for (int i = 0; i < 4; ++i) {
      float4 f = ((const float4*)src)[i];
      vt_l[r * 136 + s * 16 + 4*i]     = f2b(f.x);
      vt_l[r * 136 + s * 16 + 4*i + 1] = f2b(f.y);
      vt_l[r * 136 + s * 16 + 4*i + 2] = f2b(f.z);
      vt_l[r * 136 + s * 16 + 4*i + 3] = f2b(f.w);
    }
  }
  __syncthreads();
  #pragma unroll
  for (int p = 0; p < 2; ++p) {
    int sl = t + 256 * p;
    int qli = sl & 31, grp = sl >> 5;
    union { ushort u[8]; int4 v; } tq, tk, tv;
    #pragma unroll
    for (int j = 0; j < 8; ++j) {
      tq.u[j] = qt_l[qli * 136 + grp * 8 + j];
      tk.u[j] = kt_l[qli * 136 + grp * 8 + j];
    }
    int db = grp >> 2, ks = (grp >> 1) & 1, hh = grp & 1;
    #pragma unroll
    for (int j = 0; j < 8; ++j)
      tv.u[j] = vt_l[(16 * ks + 8 * hh + j) * 136 + 32 * db + qli];
    *(int4*)(qfb + (size_t)g * 4096 + sl * 8) = tq.v;
    *(int4*)(kfb + (size_t)g * 4096 + sl * 8) = tk.v;
    *(int4*)(vfb + (size_t)g * 4096 + sl * 8) = tv.v;
  }
}

// 4 waves/block; wave w owns 64 q rows x KV quarter w; barrier-free main loop.
// Q in LDS, V dbuf in LDS (global_load_lds), K in regs (L2-direct), o in AGPRs.
// Phase order: QK01 -> sm0 -> PV0(hold vv) -> sm1 -> PV1 (MFMA/VALU overlap).
__global__ __launch_bounds__(256, 2) void attn_kernel(
    const ushort* __restrict__ qfb, const ushort* __restrict__ kfb,
    const ushort* __restrict__ vfb, float* __restrict__ out) {
  __shared__ ushort lds[40960];  // 80KB: V [0,64KB) 4x(2x8KB dbuf), Q [64,80KB)

  const int tid = threadIdx.x;
  const int w  = tid >> 6;       // KV quarter
  const int l  = tid & 63;
  const int ql = l & 31;
  const int hi = l >> 5;

  const int bidx  = blockIdx.x;
  const int batch = bidx & 7;             // XCD b gets batch b (K+V L2-resident)
  const int qt    = bidx >> 3;            // 0..63
  const int q0    = qt * 64;
  const size_t cb = (size_t)batch * 128;  // 32-row chunk index base

  const ushort* kq = kfb + (cb + w * 32) * 4096;
  const ushort* vq = vfb + (cb + w * 32) * 4096;
  ushort* myv = lds + w * 8192;           // 16KB private V dbuf
  ushort* ldsq = lds + 32768;             // Q [2 chunks][4096]

  // ---- prologue: stage Q (16KB block-wide), V tile 0, K tile 0 ----
  {
    const ushort* qsrc = qfb + (cb + qt * 2) * 4096 + tid * 8;
    #pragma unroll
    for (int i = 0; i < 4; ++i)
      __builtin_amdgcn_global_load_lds((const GAS uint32_t*)(qsrc + i * 2048),
          (LAS uint32_t*)(ldsq + i * 2048 + tid * 8), 16, 0, 0);
  }

#define STAGE(bsel, t_) do {                                                   \
    const ushort* vsrc_ = vq + (size_t)(t_) * 4096 + l * 8;                    \
    ushort* vdst_ = myv + (bsel) * 4096 + l * 8;                               \
    _Pragma("unroll")                                                          \
    for (int i_ = 0; i_ < 8; ++i_)                                             \
      __builtin_amdgcn_global_load_lds((const GAS uint32_t*)(vsrc_ + i_ * 512),\
          (LAS uint32_t*)(vdst_ + i_ * 512), 16, 0, 0);                        \
  } while (0)

  STAGE(0, 0);
  bf16x8 kf[8];
  {
    const ushort* kt_p = kq + l * 8;
    #pragma unroll
    for (int kc = 0; kc < 8; ++kc) kf[kc] = *(const bf16x8*)(kt_p + kc * 512);
  }
  __syncthreads();   // Q visible to all waves (drains prologue loads too)

  f32x16 o[8];       // [chunk c][db]: o[c*4+db]
  #pragma unroll
  for (int i = 0; i < 8; ++i)
    #pragma unroll
    for (int r = 0; r < 16; ++r) o[i][r] = 0.f;
  float ls0 = 0.f, ls1 = 0.f;

  int buf = 0;
  for (int t = 0; t < NT; ++t) {
    if (t + 1 < NT) STAGE(buf ^ 1, t + 1);
    const bool pfK = (t + 1 < NT);
    const ushort* kp_n = kq + (size_t)(t + 1) * 4096 + l * 8;

    // ---- QK: two independent MFMA chains interleaved; K(t+1) loads folded in ----
    f32x16 st0, st1;
    #pragma unroll
    for (int r = 0; r < 16; ++r) { st0[r] = 0.f; st1[r] = 0.f; }
    const ushort* qlp = ldsq + l * 8;
    #pragma unroll
    for (int kc = 0; kc < 8; ++kc) {
      bf16x8 q0f = *(const bf16x8*)(qlp + kc * 512);
      bf16x8 q1f = *(const bf16x8*)(qlp + 4096 + kc * 512);
      st0 = __builtin_amdgcn_mfma_f32_32x32x16_bf16(kf[kc], q0f, st0, 0, 0, 0);
      st1 = __builtin_amdgcn_mfma_f32_32x32x16_bf16(kf[kc], q1f, st1, 0, 0, 0);
      if (pfK) kf[kc] = *(const bf16x8*)(kp_n + kc * 512);
    }

    // ---- diagonal mask (wave-uniform, fires on 1 of 32 iters) ----
    const int kvb = w * 1024 + t * 32;
    if (kvb == q0) {
      #pragma unroll
      for (int r = 0; r < 16; ++r) {
        int crow = (r & 3) + 8 * (r >> 2) + 4 * hi;
        if (crow == ql) st0[r] = -1e30f;
      }
    }
    if (kvb == q0 + 32) {
      #pragma unroll
      for (int r = 0; r < 16; ++r) {
        int crow = (r & 3) + 8 * (r >> 2) + 4 * hi;
        if (crow == ql) st1[r] = -1e30f;
      }
    }

    // ---- sm0: softmax + pack chunk 0 ----
    bf16x8 pa0[2];
    {
      float p0[16];
      #pragma unroll
      for (int r = 0; r < 16; ++r) p0[r] = __builtin_amdgcn_exp2f(st0[r]);
      float a = (p0[0] + p0[1]) + (p0[2] + p0[3]);
      float b = (p0[4] + p0[5]) + (p0[6] + p0[7]);
      float c = (p0[8] + p0[9]) + (p0[10] + p0[11]);
      float d = (p0[12] + p0[13]) + (p0[14] + p0[15]);
      ls0 += (a + b) + (c + d);
      uint32_t w0[4][2];
      #pragma unroll
      for (int g4 = 0; g4 < 4; ++g4) {
        w0[g4][0] = pkbf(p0[4 * g4 + 0], p0[4 * g4 + 1]);
        w0[g4][1] = pkbf(p0[4 * g4 + 2], p0[4 * g4 + 3]);
      }
      #pragma unroll
      for (int ks = 0; ks < 2; ++ks) {
        uint32_t a0 = w0[2 * ks][0], b0 = w0[2 * ks + 1][0];
        uint32_t a1 = w0[2 * ks][1], b1 = w0[2 * ks + 1][1];
        asm volatile("v_permlane32_swap_b32 %0, %1" : "+v"(a0), "+v"(b0));
        asm volatile("v_permlane32_swap_b32 %0, %1" : "+v"(a1), "+v"(b1));
        union { uint32_t u[4]; bf16x8 v; } pb;
        pb.u[0] = a0; pb.u[1] = a1; pb.u[2] = b0; pb.u[3] = b1;
        pa0[ks] = pb.v;
      }
    }

    // ---- V(t) staged? outstanding after = V(t+1) 8 + K(t+1) 8 = 16 ----
    asm volatile("s_waitcnt vmcnt(16)" ::: "memory");

    // ---- PV0: load V fragments (kept live), chunk-0 MFMAs ----
    const ushort* vlp = myv + buf * 4096 + l * 8;
    bf16x8 vv[8];
    #pragma unroll
    for (int i = 0; i < 8; ++i)
      vv[i] = *(const bf16x8*)(vlp + i * 256 * 2);   // (db*4+ks*2)*256: i*2*256
    #pragma unroll
    for (int db = 0; db < 4; ++db)
      #pragma unroll
      for (int ks = 0; ks < 2; ++ks)
        o[db] = __builtin_amdgcn_mfma_f32_32x32x16_bf16(vv[db * 2 + ks], pa0[ks], o[db], 0, 0, 0);

    // ---- sm1: softmax + pack chunk 1 (VALU overlaps PV0 MFMA execution) ----
    bf16x8 pa1[2];
    {
      float p1[16];
      #pragma unroll
      for (int r = 0; r < 16; ++r) p1[r] = __builtin_amdgcn_exp2f(st1[r]);
      float e = (p1[0] + p1[1]) + (p1[2] + p1[3]);
      float f = (p1[4] + p1[5]) + (p1[6] + p1[7]);
      float g = (p1[8] + p1[9]) + (p1[10] + p1[11]);
      float h = (p1[12] + p1[13]) + (p1[14] + p1[15]);
      ls1 += (e + f) + (g + h);
      uint32_t w1[4][2];
      #pragma unroll
      for (int g4 = 0; g4 < 4; ++g4) {
        w1[g4][0] = pkbf(p1[4 * g4 + 0], p1[4 * g4 + 1]);
        w1[g4][1] = pkbf(p1[4 * g4 + 2], p1[4 * g4 + 3]);
      }
      #pragma unroll
      for (int ks = 0; ks < 2; ++ks) {
        uint32_t c0 = w1[2 * ks][0], d0 = w1[2 * ks + 1][0];
        uint32_t c1 = w1[2 * ks][1], d1 = w1[2 * ks + 1][1];
        asm volatile("v_permlane32_swap_b32 %0, %1" : "+v"(c0), "+v"(d0));
        asm volatile("v_permlane32_swap_b32 %0, %1" : "+v"(c1), "+v"(d1));
        union { uint32_t u[4]; bf16x8 v; } pc;
        pc.u[0] = c0; pc.u[1] = c1; pc.u[2] = d0; pc.u[3] = d1;
        pa1[ks] = pc.v;
      }
    }

    // ---- PV1: reuse vv ----
    #pragma unroll
    for (int db = 0; db < 4; ++db)
      #pragma unroll
      for (int ks = 0; ks < 2; ++ks)
        o[4 + db] = __builtin_amdgcn_mfma_f32_32x32x16_bf16(vv[db * 2 + ks], pa1[ks], o[4 + db], 0, 0, 0);

    buf ^= 1;
  }
#undef STAGE

  // ---- epilogue: combine 4 quarters via LDS tree, normalize, store ----
  __syncthreads();
  float* A  = (float*)lds;          // [64 q][132] f32
  float* Bb = A + 8448;             // [64 q][132]
  float* lt = A + 16896;            // [4 w][2 hi][2 c][32 ql]
  float* Lf = A + 17408;            // inv-l per q row [64]

  lt[((w * 2 + hi) * 2 + 0) * 32 + ql] = ls0;
  lt[((w * 2 + hi) * 2 + 1) * 32 + ql] = ls1;
  __syncthreads();
  float L0 = 0.f, L1 = 0.f;
  #pragma unroll
  for (int i = 0; i < 8; ++i) {
    L0 += lt[(i * 2 + 0) * 32 + ql];
    L1 += lt[(i * 2 + 1) * 32 + ql];
  }
  if (w == 0 && hi == 0) { Lf[ql] = 1.0f / L0; Lf[32 + ql] = 1.0f / L1; }

  if (w == 3 || w == 1) {
    float* D = (w == 3) ? A : Bb;
    #pragma unroll
    for (int c = 0; c < 2; ++c)
      #pragma unroll
      for (int db = 0; db < 4; ++db)
        #pragma unroll
        for (int g4 = 0; g4 < 4; ++g4)
          *(float4*)(D + (32 * c + ql) * 132 + 32 * db + 8 * g4 + 4 * hi) =
              make_float4(o[c * 4 + db][4 * g4], o[c * 4 + db][4 * g4 + 1],
                          o[c * 4 + db][4 * g4 + 2], o[c * 4 + db][4 * g4 + 3]);
  }
  __syncthreads();
  if (w == 2 || w == 0) {
    float* D = (w == 2) ? A : Bb;
    #pragma unroll
    for (int c = 0; c < 2; ++c)
      #pragma unroll
      for (int db = 0; db < 4; ++db)
        #pragma unroll
        for (int g4 = 0; g4 < 4; ++g4) {
          float* ptr = D + (32 * c + ql) * 132 + 32 * db + 8 * g4 + 4 * hi;
          float4 tv = *(float4*)ptr;
          tv.x += o[c * 4 + db][4 * g4];
          tv.y += o[c * 4 + db][4 * g4 + 1];
          tv.z += o[c * 4 + db][4 * g4 + 2];
          tv.w += o[c * 4 + db][4 * g4 + 3];
          *(float4*)ptr = tv;
        }
  }
  __syncthreads();
  if (w == 0 || w == 2) {
    const int ch = w >> 1;
    float* outb = out + ((size_t)batch * SEQN + q0) * DIM;
    #pragma unroll
    for (int s2 = 0; s2 < 32; ++s2) {
      const int q = 32 * ch + s2;
      const float iv = Lf[q];
      float2 a2 = *(const float2*)(A + q * 132 + 2 * l);
      float2 b2 = *(const float2*)(Bb + q * 132 + 2 * l);
      *(float2*)(outb + (size_t)q * DIM + 2 * l) =
          make_float2((a2.x + b2.x) * iv, (a2.y + b2.y) * iv);
    }
  }
}

extern "C" void kernel_launch(void* const* d_in, const int* in_sizes, int n_in,
                              void* d_out, int out_size, void* d_ws, size_t ws_size,
                              hipStream_t stream) {
  (void)in_sizes; (void)n_in; (void)out_size; (void)ws_size;
  const float* qk = (const float*)d_in[0];
  const float* v  = (const float*)d_in[1];
  float* out = (float*)d_out;
  size_t nelem = (size_t)BATCH * SEQN * DIM;
  ushort* qfb = (ushort*)d_ws;
  ushort* kfb = qfb + nelem;
  ushort* vfb = kfb + nelem;
  prep_fused<<<BATCH * SEQN / 32, 256, 0, stream>>>(qk, v, qfb, kfb, vfb);
  attn_kernel<<<BATCH * (SEQN / 64), 256, 0, stream>>>(qfb, kfb, vfb, out);
}

// Round 10
// 98.472 us; speedup vs baseline: 1.0119x; 1.0119x over previous
//
#include <hip/hip_runtime.h>
#include <hip/hip_bf16.h>
#include <stdint.h>

#define BATCH 8
#define SEQN  4096
#define DIM   128
#define NT    32              // 32-kv tiles per quarter (1024 kv)

typedef __attribute__((ext_vector_type(16))) float f32x16;
typedef __bf16 bf16x8 __attribute__((ext_vector_type(8)));

#define GAS __attribute__((address_space(1)))
#define LAS __attribute__((address_space(3)))

__device__ __forceinline__ ushort f2b(float x) {
  union { float f; uint32_t u; } a; a.f = x;
  uint32_t r = a.u + 0x7fffu + ((a.u >> 16) & 1u);   // RNE
  return (ushort)(r >> 16);
}
__device__ __forceinline__ uint32_t pkbf(float a, float b) {
  union { __bf16 h[2]; uint32_t u; } x;
  x.h[0] = (__bf16)a; x.h[1] = (__bf16)b;
  return x.u;
}

// Fragment-major layouts, per 32-row chunk g (global row/32), 4096 elems/chunk:
//   Q/K: slot = (kc*2+hi)*32 + ql holds  X[g*32+ql][16*kc+8*hi + 0..7]
//   V^T: slot = (db*4+ks*2+hi)*32 + ql holds V[g*32 + 16*ks+8*hi + 0..7][32*db+ql]

__global__ __launch_bounds__(256) void prep_fused(
    const float* __restrict__ qk, const float* __restrict__ v,
    ushort* __restrict__ qfb, ushort* __restrict__ kfb, ushort* __restrict__ vfb) {
  __shared__ ushort qt_l[32 * 136];
  __shared__ ushort kt_l[32 * 136];
  __shared__ ushort vt_l[32 * 136];
  const int g = blockIdx.x;
  const int t = threadIdx.x;
  const int r = t >> 3, s = t & 7;
  {
    const float* src = qk + (size_t)g * 4096 + r * 128 + s * 16;
    float x[16];
    #pragma unroll
    for (int i = 0; i < 4; ++i) {
      float4 f = ((const float4*)src)[i];
      x[4*i] = f.x; x[4*i+1] = f.y; x[4*i+2] = f.z; x[4*i+3] = f.w;
    }
    float ss = 0.f;
    #pragma unroll
    for (int i = 0; i < 16; ++i) ss += x[i] * x[i];
    ss += __shfl_xor(ss, 1, 64);
    ss += __shfl_xor(ss, 2, 64);
    ss += __shfl_xor(ss, 4, 64);
    float rn = 1.0f / fmaxf(sqrtf(ss), 1e-12f);
    const float SC = 1.44269504088896340736f / 11.313708498984761f; // log2e/sqrt(128)
    float rs = rn * SC;
    #pragma unroll
    for (int j = 0; j < 16; ++j) {
      qt_l[r * 136 + s * 16 + j] = f2b(x[j]);
      kt_l[r * 136 + s * 16 + j] = f2b(x[j] * rs);
    }
  }
  {
    const float* src = v + (size_t)g * 4096 + r * 128 + s * 16;
    #pragma unroll
    for (int i = 0; i < 4; ++i) {
      float4 f = ((const float4*)src)[i];
      vt_l[r * 136 + s * 16 + 4*i]     = f2b(f.x);
      vt_l[r * 136 + s * 16 + 4*i + 1] = f2b(f.y);
      vt_l[r * 136 + s * 16 + 4*i + 2] = f2b(f.z);
      vt_l[r * 136 + s * 16 + 4*i + 3] = f2b(f.w);
    }
  }
  __syncthreads();
  #pragma unroll
  for (int p = 0; p < 2; ++p) {
    int sl = t + 256 * p;
    int qli = sl & 31, grp = sl >> 5;
    union { ushort u[8]; int4 v; } tq, tk, tv;
    #pragma unroll
    for (int j = 0; j < 8; ++j) {
      tq.u[j] = qt_l[qli * 136 + grp * 8 + j];
      tk.u[j] = kt_l[qli * 136 + grp * 8 + j];
    }
    int db = grp >> 2, ks = (grp >> 1) & 1, hh = grp & 1;
    #pragma unroll
    for (int j = 0; j < 8; ++j)
      tv.u[j] = vt_l[(16 * ks + 8 * hh + j) * 136 + 32 * db + qli];
    *(int4*)(qfb + (size_t)g * 4096 + sl * 8) = tq.v;
    *(int4*)(kfb + (size_t)g * 4096 + sl * 8) = tk.v;
    *(int4*)(vfb + (size_t)g * 4096 + sl * 8) = tv.v;
  }
}

// 4 waves/block; wave w owns 64 q rows x KV quarter w; barrier-free main loop.
// Q in LDS; K AND V register-prefetched direct from L2 (fragment-major).
__global__ __launch_bounds__(256, 2) void attn_kernel(
    const ushort* __restrict__ qfb, const ushort* __restrict__ kfb,
    const ushort* __restrict__ vfb, float* __restrict__ out) {
  __shared__ __align__(16) ushort lds[26752];  // Q [0,16KB); epilogue floats after

  const int tid = threadIdx.x;
  const int w  = tid >> 6;       // KV quarter
  const int l  = tid & 63;
  const int ql = l & 31;
  const int hi = l >> 5;

  const int bidx  = blockIdx.x;
  const int batch = bidx & 7;             // XCD b gets batch b (K+V L2-resident)
  const int qt    = bidx >> 3;            // 0..63
  const int q0    = qt * 64;
  const size_t cb = (size_t)batch * 128;  // 32-row chunk index base

  const ushort* kq = kfb + (cb + w * 32) * 4096;
  const ushort* vq = vfb + (cb + w * 32) * 4096;
  ushort* ldsq = lds;                     // Q [2 chunks][4096]

  // ---- prologue: stage Q (16KB block-wide); K(0), V(0) into registers ----
  {
    const ushort* qsrc = qfb + (cb + qt * 2) * 4096 + tid * 8;
    #pragma unroll
    for (int i = 0; i < 4; ++i)
      __builtin_amdgcn_global_load_lds((const GAS uint32_t*)(qsrc + i * 2048),
          (LAS uint32_t*)(ldsq + i * 2048 + tid * 8), 16, 0, 0);
  }
  bf16x8 kf[8], vv[8];
  {
    const ushort* kt_p = kq + l * 8;
    const ushort* vt_p = vq + l * 8;
    #pragma unroll
    for (int i = 0; i < 8; ++i) {
      kf[i] = *(const bf16x8*)(kt_p + i * 512);
      vv[i] = *(const bf16x8*)(vt_p + i * 512);
    }
  }
  __syncthreads();   // Q visible to all waves

  f32x16 o[8];       // [chunk c][db]: o[c*4+db]
  #pragma unroll
  for (int i = 0; i < 8; ++i)
    #pragma unroll
    for (int r = 0; r < 16; ++r) o[i][r] = 0.f;
  float ls0 = 0.f, ls1 = 0.f;

  for (int t = 0; t < NT; ++t) {
    const bool pf = (t + 1 < NT);
    const ushort* kp_n = kq + (size_t)(t + 1) * 4096 + l * 8;
    const ushort* vp_n = vq + (size_t)(t + 1) * 4096 + l * 8;

    // ---- QK: two independent MFMA chains interleaved; K(t+1) loads folded ----
    f32x16 st0, st1;
    #pragma unroll
    for (int r = 0; r < 16; ++r) { st0[r] = 0.f; st1[r] = 0.f; }
    const ushort* qlp = ldsq + l * 8;
    #pragma unroll
    for (int kc = 0; kc < 8; ++kc) {
      bf16x8 q0f = *(const bf16x8*)(qlp + kc * 512);
      bf16x8 q1f = *(const bf16x8*)(qlp + 4096 + kc * 512);
      st0 = __builtin_amdgcn_mfma_f32_32x32x16_bf16(kf[kc], q0f, st0, 0, 0, 0);
      st1 = __builtin_amdgcn_mfma_f32_32x32x16_bf16(kf[kc], q1f, st1, 0, 0, 0);
      if (pf) kf[kc] = *(const bf16x8*)(kp_n + kc * 512);
    }

    // ---- diagonal mask (wave-uniform, fires on 1 of 32 iters) ----
    const int kvb = w * 1024 + t * 32;
    if (kvb == q0) {
      #pragma unroll
      for (int r = 0; r < 16; ++r) {
        int crow = (r & 3) + 8 * (r >> 2) + 4 * hi;
        if (crow == ql) st0[r] = -1e30f;
      }
    }
    if (kvb == q0 + 32) {
      #pragma unroll
      for (int r = 0; r < 16; ++r) {
        int crow = (r & 3) + 8 * (r >> 2) + 4 * hi;
        if (crow == ql) st1[r] = -1e30f;
      }
    }

    // ---- sm0: softmax + pack chunk 0 ----
    bf16x8 pa0[2];
    {
      float p0[16];
      #pragma unroll
      for (int r = 0; r < 16; ++r) p0[r] = __builtin_amdgcn_exp2f(st0[r]);
      float a = (p0[0] + p0[1]) + (p0[2] + p0[3]);
      float b = (p0[4] + p0[5]) + (p0[6] + p0[7]);
      float c = (p0[8] + p0[9]) + (p0[10] + p0[11]);
      float d = (p0[12] + p0[13]) + (p0[14] + p0[15]);
      ls0 += (a + b) + (c + d);
      uint32_t w0[4][2];
      #pragma unroll
      for (int g4 = 0; g4 < 4; ++g4) {
        w0[g4][0] = pkbf(p0[4 * g4 + 0], p0[4 * g4 + 1]);
        w0[g4][1] = pkbf(p0[4 * g4 + 2], p0[4 * g4 + 3]);
      }
      #pragma unroll
      for (int ks = 0; ks < 2; ++ks) {
        uint32_t a0 = w0[2 * ks][0], b0 = w0[2 * ks + 1][0];
        uint32_t a1 = w0[2 * ks][1], b1 = w0[2 * ks + 1][1];
        asm volatile("v_permlane32_swap_b32 %0, %1" : "+v"(a0), "+v"(b0));
        asm volatile("v_permlane32_swap_b32 %0, %1" : "+v"(a1), "+v"(b1));
        union { uint32_t u[4]; bf16x8 v; } pb;
        pb.u[0] = a0; pb.u[1] = a1; pb.u[2] = b0; pb.u[3] = b1;
        pa0[ks] = pb.v;
      }
    }

    // ---- PV0: chunk-0 MFMAs (vv already resident) ----
    #pragma unroll
    for (int db = 0; db < 4; ++db)
      #pragma unroll
      for (int ks = 0; ks < 2; ++ks)
        o[db] = __builtin_amdgcn_mfma_f32_32x32x16_bf16(vv[db * 2 + ks], pa0[ks], o[db], 0, 0, 0);

    // ---- sm1: softmax + pack chunk 1 (VALU overlaps PV0 MFMA execution) ----
    bf16x8 pa1[2];
    {
      float p1[16];
      #pragma unroll
      for (int r = 0; r < 16; ++r) p1[r] = __builtin_amdgcn_exp2f(st1[r]);
      float e = (p1[0] + p1[1]) + (p1[2] + p1[3]);
      float f = (p1[4] + p1[5]) + (p1[6] + p1[7]);
      float g = (p1[8] + p1[9]) + (p1[10] + p1[11]);
      float h = (p1[12] + p1[13]) + (p1[14] + p1[15]);
      ls1 += (e + f) + (g + h);
      uint32_t w1[4][2];
      #pragma unroll
      for (int g4 = 0; g4 < 4; ++g4) {
        w1[g4][0] = pkbf(p1[4 * g4 + 0], p1[4 * g4 + 1]);
        w1[g4][1] = pkbf(p1[4 * g4 + 2], p1[4 * g4 + 3]);
      }
      #pragma unroll
      for (int ks = 0; ks < 2; ++ks) {
        uint32_t c0 = w1[2 * ks][0], d0 = w1[2 * ks + 1][0];
        uint32_t c1 = w1[2 * ks][1], d1 = w1[2 * ks + 1][1];
        asm volatile("v_permlane32_swap_b32 %0, %1" : "+v"(c0), "+v"(d0));
        asm volatile("v_permlane32_swap_b32 %0, %1" : "+v"(c1), "+v"(d1));
        union { uint32_t u[4]; bf16x8 v; } pc;
        pc.u[0] = c0; pc.u[1] = c1; pc.u[2] = d0; pc.u[3] = d1;
        pa1[ks] = pc.v;
      }
    }

    // ---- PV1: reuse vv; then prefetch V(t+1) into vv (renamed, WAR-safe) ----
    #pragma unroll
    for (int db = 0; db < 4; ++db)
      #pragma unroll
      for (int ks = 0; ks < 2; ++ks)
        o[4 + db] = __builtin_amdgcn_mfma_f32_32x32x16_bf16(vv[db * 2 + ks], pa1[ks], o[4 + db], 0, 0, 0);
    if (pf) {
      #pragma unroll
      for (int i = 0; i < 8; ++i) vv[i] = *(const bf16x8*)(vp_n + i * 512);
    }
  }

  // ---- epilogue: l-sums, 4-quarter combine by d-half, normalize, store ----
  __syncthreads();
  float* base = (float*)(lds + 8192);
  float* SA = base;                 // [64 q][68]
  float* SB = base + 4352;          // [64 q][68]
  float* lt = base + 8704;          // [4 w][2 hi][2 c][32 ql]
  float* Lf = base + 9216;          // inv-l per q row [64]

  lt[((w * 2 + hi) * 2 + 0) * 32 + ql] = ls0;
  lt[((w * 2 + hi) * 2 + 1) * 32 + ql] = ls1;
  __syncthreads();
  if (w == 0) {
    const int c = l >> 5, qq = l & 31;
    float L = 0.f;
    #pragma unroll
    for (int i = 0; i < 8; ++i) L += lt[(i * 2 + c) * 32 + qq];
    Lf[c * 32 + qq] = 1.0f / L;
  }

  float* outb = out + ((size_t)batch * SEQN + q0) * DIM;
  #pragma unroll
  for (int dh = 0; dh < 2; ++dh) {
    if (w == 1 || w == 3) {
      float* D = (w == 1) ? SA : SB;
      #pragma unroll
      for (int c = 0; c < 2; ++c)
        #pragma unroll
        for (int dd = 0; dd < 2; ++dd) {
          const int db = 2 * dh + dd;
          #pragma unroll
          for (int g4 = 0; g4 < 4; ++g4)
            *(float4*)(D + (32 * c + ql) * 68 + 32 * dd + 8 * g4 + 4 * hi) =
                make_float4(o[c * 4 + db][4 * g4],     o[c * 4 + db][4 * g4 + 1],
                            o[c * 4 + db][4 * g4 + 2], o[c * 4 + db][4 * g4 + 3]);
        }
    }
    __syncthreads();
    if (w == 0 || w == 2) {
      float* D = (w == 0) ? SA : SB;
      #pragma unroll
      for (int c = 0; c < 2; ++c)
        #pragma unroll
        for (int dd = 0; dd < 2; ++dd) {
          const int db = 2 * dh + dd;
          #pragma unroll
          for (int g4 = 0; g4 < 4; ++g4) {
            float* ptr = D + (32 * c + ql) * 68 + 32 * dd + 8 * g4 + 4 * hi;
            float4 tv = *(float4*)ptr;
            tv.x += o[c * 4 + db][4 * g4];
            tv.y += o[c * 4 + db][4 * g4 + 1];
            tv.z += o[c * 4 + db][4 * g4 + 2];
            tv.w += o[c * 4 + db][4 * g4 + 3];
            *(float4*)ptr = tv;
          }
        }
    }
    __syncthreads();
    #pragma unroll
    for (int rr = 0; rr < 16; ++rr) {
      const int qq = w * 16 + rr;
      const float val = (SA[qq * 68 + l] + SB[qq * 68 + l]) * Lf[qq];
      outb[(size_t)qq * DIM + dh * 64 + l] = val;
    }
    __syncthreads();
  }
}

extern "C" void kernel_launch(void* const* d_in, const int* in_sizes, int n_in,
                              void* d_out, int out_size, void* d_ws, size_t ws_size,
                              hipStream_t stream) {
  (void)in_sizes; (void)n_in; (void)out_size; (void)ws_size;
  const float* qk = (const float*)d_in[0];
  const float* v  = (const float*)d_in[1];
  float* out = (float*)d_out;
  size_t nelem = (size_t)BATCH * SEQN * DIM;
  ushort* qfb = (ushort*)d_ws;
  ushort* kfb = qfb + nelem;
  ushort* vfb = kfb + nelem;
  prep_fused<<<BATCH * SEQN / 32, 256, 0, stream>>>(qk, v, qfb, kfb, vfb);
  attn_kernel<<<BATCH * (SEQN / 64), 256, 0, stream>>>(qfb, kfb, vfb, out);
}